// Round 4
// baseline (319.162 us; speedup 1.0000x reference)
//
#include <hip/hip_runtime.h>
#include <hip/hip_bf16.h>
#include <cstdint>
#include <cstddef>

// Problem constants
constexpr int T_Q   = 32400;   // BEV queries
constexpr int T_PAD = 32512;   // padded to 254*128
constexpr int S_K   = 16896;   // feature keys (= 132*128)
constexpr int E_DIM = 256;
constexpr int HID   = 512;

typedef __bf16 bf16x8 __attribute__((ext_vector_type(8)));
typedef float  f32x4  __attribute__((ext_vector_type(4)));
typedef unsigned short ushort8v __attribute__((ext_vector_type(8)));

__device__ __forceinline__ void async16(const __hip_bfloat16* gp, __hip_bfloat16* lp) {
    __builtin_amdgcn_global_load_lds(
        (const __attribute__((address_space(1))) void*)(gp),
        (__attribute__((address_space(3))) void*)(lp), 16, 0, 0);
}

__device__ __forceinline__ float b2f(unsigned short u) {
    return __uint_as_float(((unsigned)u) << 16);
}

// ---------------------------------------------------------------------------
// prep: fused fp32->bf16 casts (q with M-pad, key, value->kv cols 256..511)
// + coalesced weight transpose to [N][K] bf16 via LDS tiles.
constexpr int NB_Q = (T_PAD * E_DIM / 4) / 256;   // 8128
constexpr int NB_K = (S_K * E_DIM / 4) / 256;     // 4224
constexpr int NB_PREP = NB_Q + NB_K + NB_K + 128;

__global__ __launch_bounds__(256) void prep(
    const float* __restrict__ q_in, const float* __restrict__ key_in,
    const float* __restrict__ val_in,
    const float* __restrict__ s0, const float* __restrict__ s1,
    const float* __restrict__ s2, const float* __restrict__ s3,
    __hip_bfloat16* __restrict__ qA, __hip_bfloat16* __restrict__ kA,
    __hip_bfloat16* __restrict__ kvB,
    __hip_bfloat16* __restrict__ d0, __hip_bfloat16* __restrict__ d1,
    __hip_bfloat16* __restrict__ d2, __hip_bfloat16* __restrict__ d3) {
    __shared__ float tb[64][65];
    const int b = blockIdx.x;
    const int tid = threadIdx.x;

    if (b < NB_Q + 2 * NB_K) {
        const float* src;
        int bl, valid, isv = 0;
        if (b < NB_Q) { src = q_in; bl = b; valid = T_Q * E_DIM; }
        else if (b < NB_Q + NB_K) { src = key_in; bl = b - NB_Q; valid = S_K * E_DIM; }
        else { src = val_in; bl = b - NB_Q - NB_K; valid = S_K * E_DIM; isv = 1; }
        int i = (bl * 256 + tid) * 4;
        float4 f = make_float4(0.f, 0.f, 0.f, 0.f);
        if (i < valid) f = *(const float4*)(src + i);
        union { ushort4 u4; __hip_bfloat16 bb[4]; } cv;
        cv.bb[0] = __float2bfloat16(f.x);
        cv.bb[1] = __float2bfloat16(f.y);
        cv.bb[2] = __float2bfloat16(f.z);
        cv.bb[3] = __float2bfloat16(f.w);
        if (isv) {
            int r = i >> 8, c = i & 255;   // v goes to kv[r][256+c]
            *(ushort4*)(kvB + (size_t)r * 512 + 256 + c) = cv.u4;
        } else {
            __hip_bfloat16* dst = (b < NB_Q) ? qA : kA;
            *(ushort4*)(dst + i) = cv.u4;
        }
        return;
    }

    // transpose: matrix m (0:q_w1 K256 N512, 1:q_w2 K512 N256, 2:k_w1, 3:k_w2)
    int tloc = b - (NB_Q + 2 * NB_K);
    int m = tloc >> 5;
    int tt = tloc & 31;
    const float* S = m == 0 ? s0 : m == 1 ? s1 : m == 2 ? s2 : s3;
    __hip_bfloat16* D = m == 0 ? d0 : m == 1 ? d1 : m == 2 ? d2 : d3;
    int Kd, Nd, kt, nt;
    if ((m & 1) == 0) { Kd = 256; Nd = 512; kt = tt & 3; nt = tt >> 2; }
    else              { Kd = 512; Nd = 256; kt = tt & 7; nt = tt >> 3; }
    int tx = tid & 63, ty = tid >> 6;
#pragma unroll
    for (int p = 0; p < 16; ++p) {
        int row = ty * 16 + p;
        tb[row][tx] = S[(size_t)(kt * 64 + row) * Nd + nt * 64 + tx];
    }
    __syncthreads();
#pragma unroll
    for (int p = 0; p < 16; ++p) {
        int row = ty * 16 + p;
        D[(size_t)(nt * 64 + row) * Kd + kt * 64 + tx] = __float2bfloat16(tb[tx][row]);
    }
}

// ---------------------------------------------------------------------------
// Dual bf16 GEMM (m97-style): handles q-rows and k-rows in one dispatch.
// tm < qtiles -> (Aq,BTq,biasq,Cq,ldcq,scaleq), else k set.
constexpr int BM = 128, BN = 128, BK = 32;

__global__ __launch_bounds__(256) void gemm_dual(
    const __hip_bfloat16* __restrict__ Aq, const __hip_bfloat16* __restrict__ Ak,
    const __hip_bfloat16* __restrict__ BTq, const __hip_bfloat16* __restrict__ BTk,
    const float* __restrict__ biasq, const float* __restrict__ biask,
    __hip_bfloat16* __restrict__ Cq, __hip_bfloat16* __restrict__ Ck,
    int K, int N, int ldcq, int ldck, int relu,
    float scaleq, float scalek, int qtiles) {
    __shared__ __hip_bfloat16 As[BM * BK];
    __shared__ __hip_bfloat16 Bs[BN * BK];

    const int ntiles = N >> 7;
    const int tm = blockIdx.x / ntiles;
    const int tn = blockIdx.x - tm * ntiles;
    const bool isq = tm < qtiles;
    const __hip_bfloat16* A  = isq ? Aq : Ak;
    const __hip_bfloat16* BT = isq ? BTq : BTk;
    const float* bias = isq ? biasq : biask;
    __hip_bfloat16* C = isq ? Cq : Ck;
    const int ldc = isq ? ldcq : ldck;
    const float scale = isq ? scaleq : scalek;
    const size_t m0 = (size_t)(isq ? tm : tm - qtiles) * BM;
    const int n0 = tn * BN;

    const int tid = threadIdx.x;
    const int w = tid >> 6, l = tid & 63;
    const int lm = l & 15, lq = l >> 4;
    const int wm = (w >> 1) << 6, wn = (w & 1) << 6;

    const int srow = l >> 2;
    const int scol = (((l & 3) ^ (srow & 3)) << 3);

    f32x4 acc[4][4] = {};

    for (int k0 = 0; k0 < K; k0 += BK) {
#pragma unroll
        for (int c = 0; c < 2; ++c) {
            int r = c * 64 + w * 16 + srow;
            async16(A  + (m0 + r) * K + k0 + scol, As + (c * 64 + w * 16) * BK);
            async16(BT + (size_t)(n0 + r) * K + k0 + scol, Bs + (c * 64 + w * 16) * BK);
        }
        __syncthreads();

        const int rsw = ((lq ^ (lm & 3)) << 3);
        bf16x8 af[4], bfr[4];
#pragma unroll
        for (int mi = 0; mi < 4; ++mi)
            af[mi] = *(const bf16x8*)(As + (wm + mi * 16 + lm) * BK + rsw);
#pragma unroll
        for (int ni = 0; ni < 4; ++ni)
            bfr[ni] = *(const bf16x8*)(Bs + (wn + ni * 16 + lm) * BK + rsw);
#pragma unroll
        for (int mi = 0; mi < 4; ++mi)
#pragma unroll
            for (int ni = 0; ni < 4; ++ni)
                acc[mi][ni] = __builtin_amdgcn_mfma_f32_16x16x32_bf16(
                    af[mi], bfr[ni], acc[mi][ni], 0, 0, 0);
        __syncthreads();
    }

#pragma unroll
    for (int ni = 0; ni < 4; ++ni) {
        int col = n0 + wn + ni * 16 + lm;
        float bv = bias[col];
#pragma unroll
        for (int mi = 0; mi < 4; ++mi) {
            size_t rowb = m0 + wm + mi * 16 + lq * 4;
#pragma unroll
            for (int r = 0; r < 4; ++r) {
                float vv = acc[mi][ni][r] + bv;
                if (relu) vv = fmaxf(vv, 0.f);
                C[(rowb + r) * ldc + col] = __float2bfloat16(vv * scale);
            }
        }
    }
}

// ---------------------------------------------------------------------------
// Attention: one wave per query, 2 points per chunk (half = l>>5 picks parity,
// sub = l&31 owns 16B of the 512B row). Fully unrolled over 16 chunks:
// all bpermutes hoisted to voffsets, ALL k gathers issued up front, v gather
// issued as each k is consumed; two-phase softmax (no online rescale).
__global__ __launch_bounds__(256) void attn_kernel(
    const __hip_bfloat16* __restrict__ q,
    const __hip_bfloat16* __restrict__ kv,
    const int* __restrict__ rf,
    const int* __restrict__ starts,
    const int* __restrict__ lens,
    float* __restrict__ out) {
    int t = blockIdx.x * 4 + (threadIdx.x >> 6);
    if (t >= T_Q) return;
    int l = threadIdx.x & 63;
    int half = l >> 5, sub = l & 31;
    int su = __builtin_amdgcn_readfirstlane(starts[t]);
    int L  = __builtin_amdgcn_readfirstlane(lens[t]);
    int nC = (L + 1) >> 1;          // 1..16 chunks

    int li = l < L - 1 ? l : L - 1; // clamp: lanes >= L hold last point's index
    int myf = rf[su + li];

    const char* base = (const char*)kv;
    unsigned voff[16];
#pragma unroll
    for (int c = 0; c < 16; ++c) {
        int f = __shfl(myf, 2 * c + half);   // index for point 2c+half
        voff[c] = ((unsigned)f << 10) + (unsigned)(sub << 4);
    }

    ushort8v qu = *(const ushort8v*)(q + (size_t)t * 256 + sub * 8);
    float qf[8];
#pragma unroll
    for (int i = 0; i < 8; ++i) qf[i] = b2f(qu[i]);

    // Phase 1: issue ALL k gathers (uniform guards; in-order completion)
    ushort8v kb[16], vb[16];
#pragma unroll
    for (int c = 0; c < 16; ++c)
        if (c < nC) kb[c] = *(const ushort8v*)(base + voff[c]);

    // Phase 2: consume k in order; issue v gather as each k is consumed
    float w[16];
#pragma unroll
    for (int c = 0; c < 16; ++c) w[c] = -1e30f;
#pragma unroll
    for (int c = 0; c < 16; ++c) {
        if (c < nC) {
            vb[c] = *(const ushort8v*)(base + voff[c] + 512);
            float wv = 0.f;
#pragma unroll
            for (int i = 0; i < 8; ++i) wv = fmaf(qf[i], b2f(kb[c][i]), wv);
            wv += __shfl_xor(wv, 1);
            wv += __shfl_xor(wv, 2);
            w[c] = (2 * c + half < L) ? wv : -1e30f;
        }
    }

    // Phase 3: softmax over all chunks (padded slots exp -> 0)
    float mx = -1e30f;
#pragma unroll
    for (int c = 0; c < 16; ++c) mx = fmaxf(mx, w[c]);
    mx = fmaxf(mx, __shfl_xor(mx, 32));
    float s = 0.f;
#pragma unroll
    for (int c = 0; c < 16; ++c) { w[c] = __expf(w[c] - mx); s += w[c]; }
    s += __shfl_xor(s, 32);

    // Phase 4: weighted v accumulate
    float a[8] = {0.f, 0.f, 0.f, 0.f, 0.f, 0.f, 0.f, 0.f};
#pragma unroll
    for (int c = 0; c < 16; ++c) {
        if (c < nC) {
#pragma unroll
            for (int i = 0; i < 8; ++i) a[i] = fmaf(w[c], b2f(vb[c][i]), a[i]);
        }
    }
#pragma unroll
    for (int i = 0; i < 8; ++i) a[i] += __shfl_xor(a[i], 32);

    float inv = 1.f / s;
    float4 o;
    o.x = (half ? a[4] : a[0]) * inv;
    o.y = (half ? a[5] : a[1]) * inv;
    o.z = (half ? a[6] : a[2]) * inv;
    o.w = (half ? a[7] : a[3]) * inv;
    *(float4*)(out + (size_t)t * 256 + sub * 8 + half * 4) = o;
}

// ---------------------------------------------------------------------------
extern "C" void kernel_launch(void* const* d_in, const int* in_sizes, int n_in,
                              void* d_out, int out_size, void* d_ws, size_t ws_size,
                              hipStream_t stream) {
    const float* q_in   = (const float*)d_in[0];
    const float* key_in = (const float*)d_in[1];
    const float* val_in = (const float*)d_in[2];
    const float* q_w1   = (const float*)d_in[3];
    const float* q_b1   = (const float*)d_in[4];
    const float* q_w2   = (const float*)d_in[5];
    const float* q_b2   = (const float*)d_in[6];
    const float* k_w1   = (const float*)d_in[7];
    const float* k_b1   = (const float*)d_in[8];
    const float* k_w2   = (const float*)d_in[9];
    const float* k_b2   = (const float*)d_in[10];
    const int* ranks_feat = (const int*)d_in[11];
    const int* starts     = (const int*)d_in[13];
    const int* lens       = (const int*)d_in[14];
    float* out = (float*)d_out;

    char* ws = (char*)d_ws;
    size_t off = 0;
    auto alloc = [&](size_t bytes) {
        char* p = ws + off;
        off += (bytes + 255) & ~(size_t)255;
        return p;
    };
    __hip_bfloat16* qA   = (__hip_bfloat16*)alloc((size_t)T_PAD * E_DIM * 2);
    __hip_bfloat16* hidQ = (__hip_bfloat16*)alloc((size_t)T_PAD * HID * 2);
    __hip_bfloat16* qMl  = (__hip_bfloat16*)alloc((size_t)T_PAD * E_DIM * 2);
    __hip_bfloat16* kA   = (__hip_bfloat16*)alloc((size_t)S_K * E_DIM * 2);
    __hip_bfloat16* hidK = (__hip_bfloat16*)alloc((size_t)S_K * HID * 2);
    __hip_bfloat16* kvB  = (__hip_bfloat16*)alloc((size_t)S_K * 512 * 2);
    __hip_bfloat16* w1qT = (__hip_bfloat16*)alloc((size_t)HID * E_DIM * 2);
    __hip_bfloat16* w2qT = (__hip_bfloat16*)alloc((size_t)E_DIM * HID * 2);
    __hip_bfloat16* w1kT = (__hip_bfloat16*)alloc((size_t)HID * E_DIM * 2);
    __hip_bfloat16* w2kT = (__hip_bfloat16*)alloc((size_t)E_DIM * HID * 2);
    (void)ws_size; (void)n_in; (void)out_size; (void)in_sizes;

    prep<<<NB_PREP, 256, 0, stream>>>(q_in, key_in, val_in,
                                      q_w1, q_w2, k_w1, k_w2,
                                      qA, kA, kvB, w1qT, w2qT, w1kT, w2kT);

    const float qscale = 0.17677669529663687f;  // 1/sqrt(32)
    const int QT = T_PAD / 128;   // 254
    const int KT = S_K / 128;     // 132

    // layer 1: [q;k] x (E->HID), relu
    gemm_dual<<<(QT + KT) * (HID / 128), 256, 0, stream>>>(
        qA, kA, w1qT, w1kT, q_b1, k_b1, hidQ, hidK,
        E_DIM, HID, HID, HID, 1, 1.0f, 1.0f, QT);
    // layer 2: [q;k] x (HID->E); q scaled by 1/sqrt(D), k written into kv cols 0..255
    gemm_dual<<<(QT + KT) * (E_DIM / 128), 256, 0, stream>>>(
        hidQ, hidK, w2qT, w2kT, q_b2, k_b2, qMl, kvB,
        HID, E_DIM, E_DIM, 512, 0, qscale, 1.0f, QT);

    attn_kernel<<<T_Q / 4, 256, 0, stream>>>(qMl, kvB, ranks_feat, starts, lens, out);
}

// Round 5
// 304.792 us; speedup vs baseline: 1.0471x; 1.0471x over previous
//
#include <hip/hip_runtime.h>
#include <hip/hip_bf16.h>
#include <cstdint>
#include <cstddef>

// Problem constants
constexpr int T_Q   = 32400;   // BEV queries
constexpr int T_PAD = 32512;   // padded to 254*128
constexpr int S_K   = 16896;   // feature keys (= 132*128)
constexpr int E_DIM = 256;
constexpr int HID   = 512;

typedef __bf16 bf16x8 __attribute__((ext_vector_type(8)));
typedef float  f32x4  __attribute__((ext_vector_type(4)));
typedef unsigned short ushort8v __attribute__((ext_vector_type(8)));

__device__ __forceinline__ void async16(const __hip_bfloat16* gp, __hip_bfloat16* lp) {
    __builtin_amdgcn_global_load_lds(
        (const __attribute__((address_space(1))) void*)(gp),
        (__attribute__((address_space(3))) void*)(lp), 16, 0, 0);
}

__device__ __forceinline__ float b2f(unsigned short u) {
    return __uint_as_float(((unsigned)u) << 16);
}

// ---------------------------------------------------------------------------
// prep: fused fp32->bf16 casts (q with M-pad, key, value->kv cols 256..511)
// + coalesced weight transpose to [N][K] bf16 via LDS tiles.
constexpr int NB_Q = (T_PAD * E_DIM / 4) / 256;   // 8128
constexpr int NB_K = (S_K * E_DIM / 4) / 256;     // 4224
constexpr int NB_PREP = NB_Q + NB_K + NB_K + 128;

__global__ __launch_bounds__(256) void prep(
    const float* __restrict__ q_in, const float* __restrict__ key_in,
    const float* __restrict__ val_in,
    const float* __restrict__ s0, const float* __restrict__ s1,
    const float* __restrict__ s2, const float* __restrict__ s3,
    __hip_bfloat16* __restrict__ qA, __hip_bfloat16* __restrict__ kA,
    __hip_bfloat16* __restrict__ kvB,
    __hip_bfloat16* __restrict__ d0, __hip_bfloat16* __restrict__ d1,
    __hip_bfloat16* __restrict__ d2, __hip_bfloat16* __restrict__ d3) {
    __shared__ float tb[64][65];
    const int b = blockIdx.x;
    const int tid = threadIdx.x;

    if (b < NB_Q + 2 * NB_K) {
        const float* src;
        int bl, valid, isv = 0;
        if (b < NB_Q) { src = q_in; bl = b; valid = T_Q * E_DIM; }
        else if (b < NB_Q + NB_K) { src = key_in; bl = b - NB_Q; valid = S_K * E_DIM; }
        else { src = val_in; bl = b - NB_Q - NB_K; valid = S_K * E_DIM; isv = 1; }
        int i = (bl * 256 + tid) * 4;
        float4 f = make_float4(0.f, 0.f, 0.f, 0.f);
        if (i < valid) f = *(const float4*)(src + i);
        union { ushort4 u4; __hip_bfloat16 bb[4]; } cv;
        cv.bb[0] = __float2bfloat16(f.x);
        cv.bb[1] = __float2bfloat16(f.y);
        cv.bb[2] = __float2bfloat16(f.z);
        cv.bb[3] = __float2bfloat16(f.w);
        if (isv) {
            int r = i >> 8, c = i & 255;   // v goes to kv[r][256+c]
            *(ushort4*)(kvB + (size_t)r * 512 + 256 + c) = cv.u4;
        } else {
            __hip_bfloat16* dst = (b < NB_Q) ? qA : kA;
            *(ushort4*)(dst + i) = cv.u4;
        }
        return;
    }

    // transpose: matrix m (0:q_w1 K256 N512, 1:q_w2 K512 N256, 2:k_w1, 3:k_w2)
    int tloc = b - (NB_Q + 2 * NB_K);
    int m = tloc >> 5;
    int tt = tloc & 31;
    const float* S = m == 0 ? s0 : m == 1 ? s1 : m == 2 ? s2 : s3;
    __hip_bfloat16* D = m == 0 ? d0 : m == 1 ? d1 : m == 2 ? d2 : d3;
    int Kd, Nd, kt, nt;
    if ((m & 1) == 0) { Kd = 256; Nd = 512; kt = tt & 3; nt = tt >> 2; }
    else              { Kd = 512; Nd = 256; kt = tt & 7; nt = tt >> 3; }
    int tx = tid & 63, ty = tid >> 6;
#pragma unroll
    for (int p = 0; p < 16; ++p) {
        int row = ty * 16 + p;
        tb[row][tx] = S[(size_t)(kt * 64 + row) * Nd + nt * 64 + tx];
    }
    __syncthreads();
#pragma unroll
    for (int p = 0; p < 16; ++p) {
        int row = ty * 16 + p;
        D[(size_t)(nt * 64 + row) * Kd + kt * 64 + tx] = __float2bfloat16(tb[tx][row]);
    }
}

// ---------------------------------------------------------------------------
// Dual bf16 GEMM, BK=64: 32 MFMA per barrier pair (small-K friendly).
// 8-way 16B-unit XOR swizzle: LDS slot (row, pu) holds logical unit pu^(row&7).
// tm < qtiles -> q set (Aq,BTq,biasq,Cq,ldcq,scaleq), else k set.
constexpr int BM = 128, BN = 128, BK2 = 64;

__global__ __launch_bounds__(256) void gemm_dual(
    const __hip_bfloat16* __restrict__ Aq, const __hip_bfloat16* __restrict__ Ak,
    const __hip_bfloat16* __restrict__ BTq, const __hip_bfloat16* __restrict__ BTk,
    const float* __restrict__ biasq, const float* __restrict__ biask,
    __hip_bfloat16* __restrict__ Cq, __hip_bfloat16* __restrict__ Ck,
    int K, int N, int ldcq, int ldck, int relu,
    float scaleq, float scalek, int qtiles) {
    __shared__ __hip_bfloat16 As[BM * BK2];   // 16 KB
    __shared__ __hip_bfloat16 Bs[BN * BK2];   // 16 KB

    const int ntiles = N >> 7;
    const int tm = blockIdx.x / ntiles;
    const int tn = blockIdx.x - tm * ntiles;
    const bool isq = tm < qtiles;
    const __hip_bfloat16* A  = isq ? Aq : Ak;
    const __hip_bfloat16* BT = isq ? BTq : BTk;
    const float* bias = isq ? biasq : biask;
    __hip_bfloat16* C = isq ? Cq : Ck;
    const int ldc = isq ? ldcq : ldck;
    const float scale = isq ? scaleq : scalek;
    const size_t m0 = (size_t)(isq ? tm : tm - qtiles) * BM;
    const int n0 = tn * BN;

    const int tid = threadIdx.x;
    const int w = tid >> 6, l = tid & 63;
    const int lm = l & 15, lq = l >> 4;
    const int wm = (w >> 1) << 6, wn = (w & 1) << 6;

    // staging: each async16 moves 8 rows x 64 cols; lane l -> row +(l>>3),
    // physical unit l&7 which must hold logical unit (l&7)^(row&7).
    const int srow8 = l >> 3;                       // row offset within 8-chunk
    const int lu8   = (((l & 7) ^ srow8) << 3);     // logical col (elements)

    f32x4 acc[4][4] = {};

    for (int k0 = 0; k0 < K; k0 += BK2) {
#pragma unroll
        for (int c = 0; c < 4; ++c) {
            int r = w * 32 + c * 8 + srow8;
            async16(A  + (m0 + r) * K + k0 + lu8, As + (w * 32 + c * 8) * BK2);
            async16(BT + (size_t)(n0 + r) * K + k0 + lu8, Bs + (w * 32 + c * 8) * BK2);
        }
        __syncthreads();

#pragma unroll
        for (int ks = 0; ks < 2; ++ks) {
            bf16x8 af[4], bfr[4];
#pragma unroll
            for (int mi = 0; mi < 4; ++mi) {
                int row = wm + mi * 16 + lm;
                int pu = (ks * 4 + lq) ^ (row & 7);
                af[mi] = *(const bf16x8*)(As + row * BK2 + pu * 8);
            }
#pragma unroll
            for (int ni = 0; ni < 4; ++ni) {
                int row = wn + ni * 16 + lm;
                int pu = (ks * 4 + lq) ^ (row & 7);
                bfr[ni] = *(const bf16x8*)(Bs + row * BK2 + pu * 8);
            }
#pragma unroll
            for (int mi = 0; mi < 4; ++mi)
#pragma unroll
                for (int ni = 0; ni < 4; ++ni)
                    acc[mi][ni] = __builtin_amdgcn_mfma_f32_16x16x32_bf16(
                        af[mi], bfr[ni], acc[mi][ni], 0, 0, 0);
        }
        __syncthreads();
    }

    // epilogue: C/D layout col = lane&15, row = (lane>>4)*4 + reg
#pragma unroll
    for (int ni = 0; ni < 4; ++ni) {
        int col = n0 + wn + ni * 16 + lm;
        float bv = bias[col];
#pragma unroll
        for (int mi = 0; mi < 4; ++mi) {
            size_t rowb = m0 + wm + mi * 16 + lq * 4;
#pragma unroll
            for (int r = 0; r < 4; ++r) {
                float vv = acc[mi][ni][r] + bv;
                if (relu) vv = fmaxf(vv, 0.f);
                C[(rowb + r) * ldc + col] = __float2bfloat16(vv * scale);
            }
        }
    }
}

// ---------------------------------------------------------------------------
// Attention (R3 structure — best measured): one wave per query, 2 points per
// chunk (half = l>>5 parity, sub = l&31 owns 16B of the 512B row), depth-3
// register pipeline, indices via ds_bpermute.
#define APREF(DK, DV, C)                                                    \
    {                                                                       \
        int pidx = ((C) << 1) + half;                                       \
        int f = __builtin_amdgcn_ds_bpermute(pidx << 2, myf);               \
        const __hip_bfloat16* bp = kv + (size_t)f * 512 + sub * 8;          \
        DK = *(const ushort8v*)bp;                                          \
        DV = *(const ushort8v*)(bp + 256);                                  \
    }

#define APROC(KB, VB, C)                                                    \
    {                                                                       \
        float wv = 0.f;                                                     \
        _Pragma("unroll") for (int i = 0; i < 8; ++i)                       \
            wv = fmaf(qf[i], b2f(KB[i]), wv);                               \
        wv += __shfl_xor(wv, 1);                                            \
        wv += __shfl_xor(wv, 2);                                            \
        float wo = __shfl_xor(wv, 32);                                      \
        int pm = ((C) << 1) + half;                                         \
        int po = ((C) << 1) + 1 - half;                                     \
        if (pm >= L) wv = -1e30f;                                           \
        if (po >= L) wo = -1e30f;                                           \
        float mn = fmaxf(m, fmaxf(wv, wo));                                 \
        float al = __expf(m - mn); m = mn;                                  \
        float p = __expf(wv - mn);                                          \
        s = fmaf(s, al, p);                                                 \
        _Pragma("unroll") for (int i = 0; i < 8; ++i)                       \
            a[i] = fmaf(p, b2f(VB[i]), a[i] * al);                          \
    }

__global__ __launch_bounds__(256) void attn_kernel(
    const __hip_bfloat16* __restrict__ q,
    const __hip_bfloat16* __restrict__ kv,
    const int* __restrict__ rf,
    const int* __restrict__ starts,
    const int* __restrict__ lens,
    float* __restrict__ out) {
    int t = blockIdx.x * 4 + (threadIdx.x >> 6);
    if (t >= T_Q) return;
    int l = threadIdx.x & 63;
    int half = l >> 5, sub = l & 31;
    int su = __builtin_amdgcn_readfirstlane(starts[t]);
    int L  = __builtin_amdgcn_readfirstlane(lens[t]);

    int li = l < L - 1 ? l : L - 1;
    int myf = rf[su + li];

    ushort8v qu = *(const ushort8v*)(q + (size_t)t * 256 + sub * 8);
    float qf[8];
#pragma unroll
    for (int i = 0; i < 8; ++i) qf[i] = b2f(qu[i]);

    float m = -INFINITY, s = 0.f;
    float a[8] = {0.f, 0.f, 0.f, 0.f, 0.f, 0.f, 0.f, 0.f};

    ushort8v k0v = {}, v0v = {}, k1v = {}, v1v = {}, k2v = {}, v2v = {};

    int nC = (L + 1) >> 1;
    APREF(k0v, v0v, 0);
    if (nC > 1) APREF(k1v, v1v, 1);
    for (int c = 0; c < nC; ++c) {
        if (c + 2 < nC) APREF(k2v, v2v, c + 2);
        APROC(k0v, v0v, c);
        k0v = k1v; v0v = v1v;
        k1v = k2v; v1v = v2v;
    }

    s += __shfl_xor(s, 32);
#pragma unroll
    for (int i = 0; i < 8; ++i) a[i] += __shfl_xor(a[i], 32);
    float inv = 1.f / s;
    float4 o;
    o.x = (half ? a[4] : a[0]) * inv;
    o.y = (half ? a[5] : a[1]) * inv;
    o.z = (half ? a[6] : a[2]) * inv;
    o.w = (half ? a[7] : a[3]) * inv;
    *(float4*)(out + (size_t)t * 256 + sub * 8 + half * 4) = o;
}

// ---------------------------------------------------------------------------
extern "C" void kernel_launch(void* const* d_in, const int* in_sizes, int n_in,
                              void* d_out, int out_size, void* d_ws, size_t ws_size,
                              hipStream_t stream) {
    const float* q_in   = (const float*)d_in[0];
    const float* key_in = (const float*)d_in[1];
    const float* val_in = (const float*)d_in[2];
    const float* q_w1   = (const float*)d_in[3];
    const float* q_b1   = (const float*)d_in[4];
    const float* q_w2   = (const float*)d_in[5];
    const float* q_b2   = (const float*)d_in[6];
    const float* k_w1   = (const float*)d_in[7];
    const float* k_b1   = (const float*)d_in[8];
    const float* k_w2   = (const float*)d_in[9];
    const float* k_b2   = (const float*)d_in[10];
    const int* ranks_feat = (const int*)d_in[11];
    const int* starts     = (const int*)d_in[13];
    const int* lens       = (const int*)d_in[14];
    float* out = (float*)d_out;

    char* ws = (char*)d_ws;
    size_t off = 0;
    auto alloc = [&](size_t bytes) {
        char* p = ws + off;
        off += (bytes + 255) & ~(size_t)255;
        return p;
    };
    __hip_bfloat16* qA   = (__hip_bfloat16*)alloc((size_t)T_PAD * E_DIM * 2);
    __hip_bfloat16* hidQ = (__hip_bfloat16*)alloc((size_t)T_PAD * HID * 2);
    __hip_bfloat16* qMl  = (__hip_bfloat16*)alloc((size_t)T_PAD * E_DIM * 2);
    __hip_bfloat16* kA   = (__hip_bfloat16*)alloc((size_t)S_K * E_DIM * 2);
    __hip_bfloat16* hidK = (__hip_bfloat16*)alloc((size_t)S_K * HID * 2);
    __hip_bfloat16* kvB  = (__hip_bfloat16*)alloc((size_t)S_K * 512 * 2);
    __hip_bfloat16* w1qT = (__hip_bfloat16*)alloc((size_t)HID * E_DIM * 2);
    __hip_bfloat16* w2qT = (__hip_bfloat16*)alloc((size_t)E_DIM * HID * 2);
    __hip_bfloat16* w1kT = (__hip_bfloat16*)alloc((size_t)HID * E_DIM * 2);
    __hip_bfloat16* w2kT = (__hip_bfloat16*)alloc((size_t)E_DIM * HID * 2);
    (void)ws_size; (void)n_in; (void)out_size; (void)in_sizes;

    prep<<<NB_PREP, 256, 0, stream>>>(q_in, key_in, val_in,
                                      q_w1, q_w2, k_w1, k_w2,
                                      qA, kA, kvB, w1qT, w2qT, w1kT, w2kT);

    const float qscale = 0.17677669529663687f;  // 1/sqrt(32)
    const int QT = T_PAD / 128;   // 254
    const int KT = S_K / 128;     // 132

    // layer 1: [q;k] x (E->HID), relu
    gemm_dual<<<(QT + KT) * (HID / 128), 256, 0, stream>>>(
        qA, kA, w1qT, w1kT, q_b1, k_b1, hidQ, hidK,
        E_DIM, HID, HID, HID, 1, 1.0f, 1.0f, QT);
    // layer 2: [q;k] x (HID->E); q scaled by 1/sqrt(D), k written into kv cols 0..255
    gemm_dual<<<(QT + KT) * (E_DIM / 128), 256, 0, stream>>>(
        hidQ, hidK, w2qT, w2kT, q_b2, k_b2, qMl, kvB,
        HID, E_DIM, E_DIM, 512, 0, qscale, 1.0f, QT);

    attn_kernel<<<T_Q / 4, 256, 0, stream>>>(qMl, kvB, ranks_feat, starts, lens, out);
}

// Round 6
// 293.898 us; speedup vs baseline: 1.0860x; 1.0371x over previous
//
#include <hip/hip_runtime.h>
#include <hip/hip_bf16.h>
#include <cstdint>
#include <cstddef>

// Problem constants
constexpr int T_Q   = 32400;   // BEV queries
constexpr int T_PAD = 32512;   // padded (multiple of 64)
constexpr int S_K   = 16896;   // feature keys
constexpr int E_DIM = 256;
constexpr int HID   = 512;

typedef __bf16 bf16x8 __attribute__((ext_vector_type(8)));
typedef float  f32x4  __attribute__((ext_vector_type(4)));
typedef unsigned short ushort8v __attribute__((ext_vector_type(8)));

__device__ __forceinline__ void async16(const __hip_bfloat16* gp, __hip_bfloat16* lp) {
    __builtin_amdgcn_global_load_lds(
        (const __attribute__((address_space(1))) void*)(gp),
        (__attribute__((address_space(3))) void*)(lp), 16, 0, 0);
}

__device__ __forceinline__ float b2f(unsigned short u) {
    return __uint_as_float(((unsigned)u) << 16);
}

// ---------------------------------------------------------------------------
// prep: v cast into kv cols 256..511 + weight transpose to [N][K] bf16.
constexpr int NB_K = (S_K * E_DIM / 4) / 256;     // 4224
constexpr int NB_PREP = NB_K + 128;

__global__ __launch_bounds__(256) void prep(
    const float* __restrict__ val_in,
    const float* __restrict__ s0, const float* __restrict__ s1,
    const float* __restrict__ s2, const float* __restrict__ s3,
    __hip_bfloat16* __restrict__ kvB,
    __hip_bfloat16* __restrict__ d0, __hip_bfloat16* __restrict__ d1,
    __hip_bfloat16* __restrict__ d2, __hip_bfloat16* __restrict__ d3) {
    __shared__ float tb[64][65];
    const int b = blockIdx.x;
    const int tid = threadIdx.x;

    if (b < NB_K) {
        int i = (b * 256 + tid) * 4;
        float4 f = *(const float4*)(val_in + i);
        union { ushort4 u4; __hip_bfloat16 bb[4]; } cv;
        cv.bb[0] = __float2bfloat16(f.x);
        cv.bb[1] = __float2bfloat16(f.y);
        cv.bb[2] = __float2bfloat16(f.z);
        cv.bb[3] = __float2bfloat16(f.w);
        int r = i >> 8, c = i & 255;   // v goes to kv[r][256+c]
        *(ushort4*)(kvB + (size_t)r * 512 + 256 + c) = cv.u4;
        return;
    }

    // transpose: matrix m (0:q_w1 K256 N512, 1:q_w2 K512 N256, 2:k_w1, 3:k_w2)
    int tloc = b - NB_K;
    int m = tloc >> 5;
    int tt = tloc & 31;
    const float* S = m == 0 ? s0 : m == 1 ? s1 : m == 2 ? s2 : s3;
    __hip_bfloat16* D = m == 0 ? d0 : m == 1 ? d1 : m == 2 ? d2 : d3;
    int Kd, Nd, kt, nt;
    if ((m & 1) == 0) { Kd = 256; Nd = 512; kt = tt & 3; nt = tt >> 2; }
    else              { Kd = 512; Nd = 256; kt = tt & 7; nt = tt >> 3; }
    int tx = tid & 63, ty = tid >> 6;
#pragma unroll
    for (int p = 0; p < 16; ++p) {
        int row = ty * 16 + p;
        tb[row][tx] = S[(size_t)(kt * 64 + row) * Nd + nt * 64 + tx];
    }
    __syncthreads();
#pragma unroll
    for (int p = 0; p < 16; ++p) {
        int row = ty * 16 + p;
        D[(size_t)(nt * 64 + row) * Kd + kt * 64 + tx] = __float2bfloat16(tb[tx][row]);
    }
}

// ---------------------------------------------------------------------------
// GEMM geometry: BM=64, BN=256, BK=64. 8-way 16B-unit XOR swizzle
// (LDS slot (row, pu) holds logical unit pu^(row&7)); stride 64 elements.

// Layer 1: A fp32 (fused cast, zero-pad past rowlim), dual q/k, relu, ld=512.
__global__ __launch_bounds__(256) void gemm1(
    const float* __restrict__ Aq, const float* __restrict__ Ak,
    const __hip_bfloat16* __restrict__ BTq, const __hip_bfloat16* __restrict__ BTk,
    const float* __restrict__ biasq, const float* __restrict__ biask,
    __hip_bfloat16* __restrict__ Cq, __hip_bfloat16* __restrict__ Ck,
    int qtiles) {
    __shared__ __hip_bfloat16 As[64 * 64];    // 8 KB
    __shared__ __hip_bfloat16 Bs[256 * 64];   // 32 KB

    const int tm = blockIdx.x >> 1;           // ntiles = 512/256 = 2
    const int tn = blockIdx.x & 1;
    const bool isq = tm < qtiles;
    const float* A  = isq ? Aq : Ak;
    const __hip_bfloat16* BT = isq ? BTq : BTk;
    const float* bias = isq ? biasq : biask;
    __hip_bfloat16* C = isq ? Cq : Ck;
    const int mrow0 = (isq ? tm : tm - qtiles) * 64;
    const int rowlim = isq ? T_Q : S_K;
    const int n0 = tn * 256;

    const int tid = threadIdx.x;
    const int w = tid >> 6, l = tid & 63;
    const int lm = l & 15, lq = l >> 4;
    const int wn = w * 64;
    const int srow8 = l >> 3;                 // 0..7
    const int u8 = l & 7;
    const int pu8 = u8 ^ srow8;               // phys unit for A write
    const int scolB = (u8 ^ srow8) << 3;      // swizzled source col for B stage

    f32x4 acc[4][4] = {};

    for (int k0 = 0; k0 < 256; k0 += 64) {
        // A: fp32 -> bf16 in-register, ds_write_b128 (wave w: rows 16w..16w+15)
#pragma unroll
        for (int c = 0; c < 2; ++c) {
            int r = w * 16 + c * 8 + srow8;
            int gr = mrow0 + r;
            float4 f0 = make_float4(0.f, 0.f, 0.f, 0.f);
            float4 f1 = make_float4(0.f, 0.f, 0.f, 0.f);
            if (gr < rowlim) {
                const float* ap = A + (size_t)gr * 256 + k0 + u8 * 8;
                f0 = *(const float4*)ap;
                f1 = *(const float4*)(ap + 4);
            }
            union { bf16x8 v; __hip_bfloat16 b[8]; } cv;
            cv.b[0] = __float2bfloat16(f0.x); cv.b[1] = __float2bfloat16(f0.y);
            cv.b[2] = __float2bfloat16(f0.z); cv.b[3] = __float2bfloat16(f0.w);
            cv.b[4] = __float2bfloat16(f1.x); cv.b[5] = __float2bfloat16(f1.y);
            cv.b[6] = __float2bfloat16(f1.z); cv.b[7] = __float2bfloat16(f1.w);
            *(bf16x8*)(As + r * 64 + pu8 * 8) = cv.v;
        }
        // B: async16 (wave w: rows 64w..64w+63, 8 chunks of 8 rows)
#pragma unroll
        for (int c = 0; c < 8; ++c) {
            int r = w * 64 + c * 8 + srow8;
            async16(BT + (size_t)(n0 + r) * 256 + k0 + scolB,
                    Bs + (w * 64 + c * 8) * 64);
        }
        __syncthreads();

#pragma unroll
        for (int ks = 0; ks < 2; ++ks) {
            bf16x8 af[4], bfr[4];
#pragma unroll
            for (int mi = 0; mi < 4; ++mi) {
                int row = mi * 16 + lm;
                int pu = (ks * 4 + lq) ^ (row & 7);
                af[mi] = *(const bf16x8*)(As + row * 64 + pu * 8);
            }
#pragma unroll
            for (int ni = 0; ni < 4; ++ni) {
                int row = wn + ni * 16 + lm;
                int pu = (ks * 4 + lq) ^ (row & 7);
                bfr[ni] = *(const bf16x8*)(Bs + row * 64 + pu * 8);
            }
#pragma unroll
            for (int mi = 0; mi < 4; ++mi)
#pragma unroll
                for (int ni = 0; ni < 4; ++ni)
                    acc[mi][ni] = __builtin_amdgcn_mfma_f32_16x16x32_bf16(
                        af[mi], bfr[ni], acc[mi][ni], 0, 0, 0);
        }
        __syncthreads();
    }

#pragma unroll
    for (int ni = 0; ni < 4; ++ni) {
        int col = n0 + wn + ni * 16 + lm;
        float bv = bias[col];
#pragma unroll
        for (int mi = 0; mi < 4; ++mi) {
            size_t rowb = (size_t)mrow0 + mi * 16 + lq * 4;
#pragma unroll
            for (int r = 0; r < 4; ++r) {
                float vv = fmaxf(acc[mi][ni][r] + bv, 0.f);   // relu
                C[(rowb + r) * HID + col] = __float2bfloat16(vv);
            }
        }
    }
}

// Layer 2: A bf16 (async16), dual q/k, no relu, per-side ldc/scale.
__global__ __launch_bounds__(256) void gemm2(
    const __hip_bfloat16* __restrict__ Aq, const __hip_bfloat16* __restrict__ Ak,
    const __hip_bfloat16* __restrict__ BTq, const __hip_bfloat16* __restrict__ BTk,
    const float* __restrict__ biasq, const float* __restrict__ biask,
    __hip_bfloat16* __restrict__ Cq, __hip_bfloat16* __restrict__ Ck,
    float scaleq, int qtiles) {
    __shared__ __hip_bfloat16 As[64 * 64];
    __shared__ __hip_bfloat16 Bs[256 * 64];

    const int tm = blockIdx.x;                // ntiles = 256/256 = 1
    const bool isq = tm < qtiles;
    const __hip_bfloat16* A  = isq ? Aq : Ak;
    const __hip_bfloat16* BT = isq ? BTq : BTk;
    const float* bias = isq ? biasq : biask;
    __hip_bfloat16* C = isq ? Cq : Ck;
    const int ldc = isq ? E_DIM : 512;
    const float scale = isq ? scaleq : 1.0f;
    const int mrow0 = (isq ? tm : tm - qtiles) * 64;

    const int tid = threadIdx.x;
    const int w = tid >> 6, l = tid & 63;
    const int lm = l & 15, lq = l >> 4;
    const int wn = w * 64;
    const int srow8 = l >> 3;
    const int u8 = l & 7;
    const int scol = (u8 ^ srow8) << 3;

    f32x4 acc[4][4] = {};

    for (int k0 = 0; k0 < 512; k0 += 64) {
#pragma unroll
        for (int c = 0; c < 2; ++c) {
            int r = w * 16 + c * 8 + srow8;
            async16(A + (size_t)(mrow0 + r) * 512 + k0 + scol,
                    As + (w * 16 + c * 8) * 64);
        }
#pragma unroll
        for (int c = 0; c < 8; ++c) {
            int r = w * 64 + c * 8 + srow8;
            async16(BT + (size_t)r * 512 + k0 + scol,
                    Bs + (w * 64 + c * 8) * 64);
        }
        __syncthreads();

#pragma unroll
        for (int ks = 0; ks < 2; ++ks) {
            bf16x8 af[4], bfr[4];
#pragma unroll
            for (int mi = 0; mi < 4; ++mi) {
                int row = mi * 16 + lm;
                int pu = (ks * 4 + lq) ^ (row & 7);
                af[mi] = *(const bf16x8*)(As + row * 64 + pu * 8);
            }
#pragma unroll
            for (int ni = 0; ni < 4; ++ni) {
                int row = wn + ni * 16 + lm;
                int pu = (ks * 4 + lq) ^ (row & 7);
                bfr[ni] = *(const bf16x8*)(Bs + row * 64 + pu * 8);
            }
#pragma unroll
            for (int mi = 0; mi < 4; ++mi)
#pragma unroll
                for (int ni = 0; ni < 4; ++ni)
                    acc[mi][ni] = __builtin_amdgcn_mfma_f32_16x16x32_bf16(
                        af[mi], bfr[ni], acc[mi][ni], 0, 0, 0);
        }
        __syncthreads();
    }

#pragma unroll
    for (int ni = 0; ni < 4; ++ni) {
        int col = wn + ni * 16 + lm;
        float bv = bias[col];
#pragma unroll
        for (int mi = 0; mi < 4; ++mi) {
            size_t rowb = (size_t)mrow0 + mi * 16 + lq * 4;
#pragma unroll
            for (int r = 0; r < 4; ++r) {
                float vv = (acc[mi][ni][r] + bv) * scale;
                C[(rowb + r) * ldc + col] = __float2bfloat16(vv);
            }
        }
    }
}

// ---------------------------------------------------------------------------
// Attention: one wave per query, ONE point per chunk, full-wave 1 KB load:
// lanes 0-31 carry the point's k row, lanes 32-63 its v row. Score computed on
// k-half, crossed to v-half via shfl_xor(32). 6-deep register rotation keeps
// ~5 wave-loads in flight. Online softmax per head (4-lane groups).
#define PREF1(BUF, C)                                                        \
    {                                                                        \
        int f_ = __shfl(myf, (C));                                           \
        BUF = *(const ushort8v*)(kv + ((size_t)f_ << 9) + (l << 3));         \
    }

#define PROC1(BUF)                                                           \
    {                                                                        \
        float wv = 0.f;                                                      \
        _Pragma("unroll") for (int i = 0; i < 8; ++i)                        \
            wv = fmaf(qf[i], b2f(BUF[i]), wv);                               \
        wv += __shfl_xor(wv, 1);                                             \
        wv += __shfl_xor(wv, 2);                                             \
        float t2 = __shfl_xor(wv, 32);                                       \
        float sc = half ? t2 : wv;                                           \
        float mn = fmaxf(m, sc);                                             \
        float al = __expf(m - mn);                                           \
        float p  = __expf(sc - mn);                                          \
        m = mn;                                                              \
        s = fmaf(s, al, p);                                                  \
        _Pragma("unroll") for (int i = 0; i < 8; ++i)                        \
            a[i] = fmaf(p, b2f(BUF[i]), a[i] * al);                          \
    }

#define STEP(BUF, J)                                                         \
    if (c + (J) < L) {                                                       \
        PROC1(BUF);                                                          \
        if (c + (J) + 6 < L) PREF1(BUF, c + (J) + 6);                        \
    }

__global__ __launch_bounds__(256) void attn_kernel(
    const __hip_bfloat16* __restrict__ q,
    const __hip_bfloat16* __restrict__ kv,
    const int* __restrict__ rf,
    const int* __restrict__ starts,
    const int* __restrict__ lens,
    float* __restrict__ out) {
    int t = blockIdx.x * 4 + (threadIdx.x >> 6);
    if (t >= T_Q) return;
    int l = threadIdx.x & 63;
    int half = l >> 5, sub = l & 31;
    int su = __builtin_amdgcn_readfirstlane(starts[t]);
    int L  = __builtin_amdgcn_readfirstlane(lens[t]);

    int li = l < L - 1 ? l : L - 1;   // clamp so any shfl source is valid
    int myf = rf[su + li];

    ushort8v qu = *(const ushort8v*)(q + (size_t)t * 256 + sub * 8);
    float qf[8];
#pragma unroll
    for (int i = 0; i < 8; ++i) qf[i] = b2f(qu[i]);

    float m = -INFINITY, s = 0.f;
    float a[8] = {0.f, 0.f, 0.f, 0.f, 0.f, 0.f, 0.f, 0.f};

    ushort8v b0 = {}, b1 = {}, b2 = {}, b3 = {}, b4 = {}, b5 = {};
    PREF1(b0, 0);
    if (L > 1) PREF1(b1, 1);
    if (L > 2) PREF1(b2, 2);
    if (L > 3) PREF1(b3, 3);
    if (L > 4) PREF1(b4, 4);
    if (L > 5) PREF1(b5, 5);

    for (int c = 0; c < L; c += 6) {
        STEP(b0, 0)
        STEP(b1, 1)
        STEP(b2, 2)
        STEP(b3, 3)
        STEP(b4, 4)
        STEP(b5, 5)
    }

    // v-half lanes hold the output: lane 32+x owns out dims x*8..x*8+7
    if (half) {
        float inv = 1.f / s;
        float* op = out + (size_t)t * 256 + sub * 8;
        float4 o0, o1;
        o0.x = a[0] * inv; o0.y = a[1] * inv; o0.z = a[2] * inv; o0.w = a[3] * inv;
        o1.x = a[4] * inv; o1.y = a[5] * inv; o1.z = a[6] * inv; o1.w = a[7] * inv;
        *(float4*)op = o0;
        *(float4*)(op + 4) = o1;
    }
}

// ---------------------------------------------------------------------------
extern "C" void kernel_launch(void* const* d_in, const int* in_sizes, int n_in,
                              void* d_out, int out_size, void* d_ws, size_t ws_size,
                              hipStream_t stream) {
    const float* q_in   = (const float*)d_in[0];
    const float* key_in = (const float*)d_in[1];
    const float* val_in = (const float*)d_in[2];
    const float* q_w1   = (const float*)d_in[3];
    const float* q_b1   = (const float*)d_in[4];
    const float* q_w2   = (const float*)d_in[5];
    const float* q_b2   = (const float*)d_in[6];
    const float* k_w1   = (const float*)d_in[7];
    const float* k_b1   = (const float*)d_in[8];
    const float* k_w2   = (const float*)d_in[9];
    const float* k_b2   = (const float*)d_in[10];
    const int* ranks_feat = (const int*)d_in[11];
    const int* starts     = (const int*)d_in[13];
    const int* lens       = (const int*)d_in[14];
    float* out = (float*)d_out;

    char* ws = (char*)d_ws;
    size_t off = 0;
    auto alloc = [&](size_t bytes) {
        char* p = ws + off;
        off += (bytes + 255) & ~(size_t)255;
        return p;
    };
    __hip_bfloat16* hidQ = (__hip_bfloat16*)alloc((size_t)T_PAD * HID * 2);
    __hip_bfloat16* hidK = (__hip_bfloat16*)alloc((size_t)S_K * HID * 2);
    __hip_bfloat16* qMl  = (__hip_bfloat16*)alloc((size_t)T_PAD * E_DIM * 2);
    __hip_bfloat16* kvB  = (__hip_bfloat16*)alloc((size_t)S_K * 512 * 2);
    __hip_bfloat16* w1qT = (__hip_bfloat16*)alloc((size_t)HID * E_DIM * 2);
    __hip_bfloat16* w2qT = (__hip_bfloat16*)alloc((size_t)E_DIM * HID * 2);
    __hip_bfloat16* w1kT = (__hip_bfloat16*)alloc((size_t)HID * E_DIM * 2);
    __hip_bfloat16* w2kT = (__hip_bfloat16*)alloc((size_t)E_DIM * HID * 2);
    (void)ws_size; (void)n_in; (void)out_size; (void)in_sizes;

    prep<<<NB_PREP, 256, 0, stream>>>(val_in, q_w1, q_w2, k_w1, k_w2,
                                      kvB, w1qT, w2qT, w1kT, w2kT);

    const float qscale = 0.17677669529663687f;  // 1/sqrt(32)
    const int QT = T_PAD / 64;   // 508
    const int KT = S_K / 64;     // 264

    gemm1<<<(QT + KT) * 2, 256, 0, stream>>>(
        q_in, key_in, w1qT, w1kT, q_b1, k_b1, hidQ, hidK, QT);
    gemm2<<<QT + KT, 256, 0, stream>>>(
        hidQ, hidK, w2qT, w2kT, q_b2, k_b2, qMl, kvB, qscale, QT);

    attn_kernel<<<T_Q / 4, 256, 0, stream>>>(qMl, kvB, ranks_feat, starts, lens, out);
}